// Round 6
// baseline (187.336 us; speedup 1.0000x reference)
//
#include <hip/hip_runtime.h>
#include <math.h>

#define DPI 3.14159265358979323846
#define RPB 4                                   // rows per persistent block

__device__ __forceinline__ float2 cmul(float2 a, float2 b) {
    return make_float2(a.x*b.x - a.y*b.y, a.x*b.y + a.y*b.x);
}
__device__ __forceinline__ float2 cadd(float2 a, float2 b){ return make_float2(a.x+b.x, a.y+b.y); }
__device__ __forceinline__ float2 csub(float2 a, float2 b){ return make_float2(a.x-b.x, a.y-b.y); }

// W_32^m = (cos, -sin)(2*pi*m/32), m = 0..15
__device__ const float TW32R[16] = {
    1.0f, 0.98078528040323045f, 0.92387953251128676f, 0.83146961230254524f,
    0.70710678118654752f, 0.55557023301960222f, 0.38268343236508977f, 0.19509032201612827f,
    0.0f, -0.19509032201612827f, -0.38268343236508977f, -0.55557023301960222f,
    -0.70710678118654752f, -0.83146961230254524f, -0.92387953251128676f, -0.98078528040323045f };
__device__ const float TW32I[16] = {
    0.0f, -0.19509032201612827f, -0.38268343236508977f, -0.55557023301960222f,
    -0.70710678118654752f, -0.83146961230254524f, -0.92387953251128676f, -0.98078528040323045f,
    -1.0f, -0.98078528040323045f, -0.92387953251128676f, -0.83146961230254524f,
    -0.70710678118654752f, -0.55557023301960222f, -0.38268343236508977f, -0.19509032201612827f };

__device__ const int BR4[16] = {0,8,4,12,2,10,6,14,1,9,5,13,3,11,7,15};

// DIF stage for register FFT of size 16, butterfly half-span H.
template<int H>
__device__ __forceinline__ void stage16(float2* y) {
    #pragma unroll
    for (int g = 0; g < 16; g += 2*H) {
        #pragma unroll
        for (int j = 0; j < H; j++) {
            float2 u = y[g+j], v = y[g+j+H];
            y[g+j] = cadd(u, v);
            float2 d = csub(u, v);
            const int m = j * (16 / H);
            y[g+j+H] = (j == 0) ? d : cmul(d, make_float2(TW32R[m], TW32I[m]));
        }
    }
}
__device__ __forceinline__ void fft16(float2* y) {
    stage16<8>(y); stage16<4>(y); stage16<2>(y); stage16<1>(y);
}   // y[p] = OUT[BR4[p]]

// wp[m] = w^m, m=0..15, mult depth <= 3
__device__ __forceinline__ void pow16(float2 w, float2* wp) {
    wp[0] = make_float2(1.f, 0.f);
    wp[1] = w;
    wp[2] = cmul(w, w);
    wp[3] = cmul(wp[2], w);
    wp[4] = cmul(wp[2], wp[2]);
    wp[5] = cmul(wp[4], wp[1]);
    wp[6] = cmul(wp[4], wp[2]);
    wp[7] = cmul(wp[4], wp[3]);
    wp[8] = cmul(wp[4], wp[4]);
    wp[9] = cmul(wp[8], wp[1]);
    wp[10] = cmul(wp[8], wp[2]);
    wp[11] = cmul(wp[8], wp[3]);
    wp[12] = cmul(wp[8], wp[4]);
    wp[13] = cmul(wp[8], wp[5]);
    wp[14] = cmul(wp[8], wp[6]);
    wp[15] = cmul(wp[8], wp[7]);
}

// ws layout (float2): [0,512) W_8192^u | [512,544) W_512^j | [544,1568) W_2048^t | [1568,1576) W_16384^i
static __global__ void init_tw(float2* __restrict__ ws) {
    int g = blockIdx.x * 1024 + threadIdx.x;
    if (g < 512) {
        ws[g] = make_float2((float)cos(DPI*g/4096.0), (float)(-sin(DPI*g/4096.0)));
    } else if (g < 544) {
        int j = g - 512;
        ws[g] = make_float2((float)cos(DPI*j/256.0), (float)(-sin(DPI*j/256.0)));
    } else if (g < 1568) {
        int q = g - 544;
        ws[g] = make_float2((float)cos(DPI*q/1024.0), (float)(-sin(DPI*q/1024.0)));
    } else if (g < 1576) {
        int i = g - 1568;
        ws[g] = make_float2((float)cos(DPI*i/8192.0), (float)(-sin(DPI*i/8192.0)));
    }
}

__launch_bounds__(1024, 4)   // 4 waves/EU (LDS-capped anyway) -> 128 VGPR budget
static __global__ void chisq_kernel(const float* __restrict__ tmpl,
                                    const float* __restrict__ strn,
                                    const float2* __restrict__ ws,
                                    float* __restrict__ out,
                                    int rows)
{
    __shared__ float2 Z[16384];                 // 128 KiB: [0,8192)=strain, [8192,16384)=template
    float* F = reinterpret_cast<float*>(Z);
    int*   I = reinterpret_cast<int*>(Z);

    const int t    = threadIdx.x;               // 0..1023
    const int half = t >> 9;                    // 0 = strain, 1 = template
    const int u    = t & 511;
    const float ALPHA = 1.1920928955078125e-7f; // 4*DF/fs^2 = 2^-23

    const float2* tw8192 = ws;                  // W_8192^u, u<512
    const float2* tw512  = ws + 512;            // W_512^j,  j<32
    const float2* twC    = ws + 544;            // W_2048^t, t<1024
    const float2* twI    = ws + 1568;           // W_16384^i, i<8

    float2* Zh = Z + (half << 13);
    const float* sig = half ? tmpl : strn;
    const float2 cv = twC[t];                   // row-invariant unpack twiddle

    const int r0 = blockIdx.x * RPB;

    // ---- prologue: load first row's stage-1 inputs into registers ----
    float2 P[16];
    if (r0 < rows) {
        const float2* x = reinterpret_cast<const float2*>(sig + (size_t)r0 * 16384);
        #pragma unroll
        for (int n1 = 0; n1 < 16; n1++) P[n1] = x[n1*512 + u];
    }

    for (int rr = 0; rr < RPB; rr++) {
        const int row = r0 + rr;
        if (row >= rows) break;                  // block-uniform

        // -------- stage 1: fft16 over n1 (register data), twiddle W_8192^{u*k1} --------
        fft16(P);                                // pure-register; overlaps prev iter's tail
        __syncthreads();                         // prev iteration's LDS consumers done
        {
            float2 wp[16]; pow16(tw8192[u], wp);
            #pragma unroll
            for (int p = 0; p < 16; p++) {
                int k1 = BR4[p];
                float2 val = P[p];
                if (k1 > 0) val = cmul(val, wp[k1]);
                Zh[(u << 4) | (k1 ^ (u & 15))] = val;   // L1[u][k1], swizzled
            }
        }

        // -------- prefetch next row's inputs (latency hides under stages 2-3 + reductions) --------
        if (rr + 1 < RPB && row + 1 < rows) {
            const float2* xn = reinterpret_cast<const float2*>(sig + (size_t)(row + 1) * 16384);
            #pragma unroll
            for (int n1 = 0; n1 < 16; n1++) P[n1] = xn[n1*512 + u];
        }
        __syncthreads();

        float2 y[16];

        // -------- stage 2: fft16 over n2 (u = n2*32 + j), twiddle W_512^{j*k2} --------
        const int k1s = u >> 5, js = u & 31;
        #pragma unroll
        for (int n2 = 0; n2 < 16; n2++)
            y[n2] = Zh[((n2*32 + js) << 4) | (k1s ^ (js & 15))];
        __syncthreads();                          // all L1 reads done before L2 writes
        fft16(y);
        {
            float2 wq[16]; pow16(tw512[js], wq);
            #pragma unroll
            for (int p = 0; p < 16; p++) {
                int k2 = BR4[p];
                float2 val = y[p];
                if (k2 > 0) val = cmul(val, wq[k2]);
                Zh[(k1s << 9) + (k2 << 5) + (js ^ k2)] = val;  // L2[k1][k2][j], swizzled
            }
        }
        __syncthreads();

        // -------- stage 3: radix-2 (j2, j2+16) fused into the load + fft16 over j2 --------
        const int f = u >> 8, k1t = (u >> 4) & 15, k2t = u & 15;
        const int base = (k1t << 9) + (k2t << 5);
        if (f == 0) {
            #pragma unroll
            for (int j2 = 0; j2 < 16; j2++) {
                float2 a = Zh[base + (j2 ^ k2t)];
                float2 b = Zh[base + (j2 ^ k2t) + 16];
                y[j2] = cadd(a, b);
            }
        } else {
            #pragma unroll
            for (int j2 = 0; j2 < 16; j2++) {
                float2 a = Zh[base + (j2 ^ k2t)];
                float2 b = Zh[base + (j2 ^ k2t) + 16];
                y[j2] = cmul(csub(a, b), make_float2(TW32R[j2], TW32I[j2]));
            }
        }
        __syncthreads();                          // all L2 reads done before spectrum store
        fft16(y);
        #pragma unroll
        for (int p = 0; p < 16; p++) {
            int s2 = BR4[p];
            int k = k1t + (k2t << 4) + (f << 8) + (s2 << 9);
            Zh[(k & ~31) | ((k & 31) ^ ((k >> 5) & 31))] = y[p];  // natural k, swizzled low5
        }
        __syncthreads();                          // both spectra ready

        // -------- rfft unpack of both spectra + pointwise products, 8 bins/thread --------
        float2* ZS = Z;
        float2* ZH = Z + 8192;
        float2 zs0 = ZS[0], zh0 = ZH[0];
        const float s_nyq = zs0.x - zs0.y;
        const float h_nyq = zh0.x - zh0.y;

        float hh[8], hs[8];                       // |H|^2, Re(conj(H)*S)
        #pragma unroll
        for (int i = 0; i < 8; i++) {
            int k = (t << 3) + i;
            int m = (8192 - k) & 8191;
            int ak = (k & ~31) | ((k & 31) ^ ((k >> 5) & 31));
            int am = (m & ~31) | ((m & 31) ^ ((m >> 5) & 31));
            float2 As = ZS[ak], Bs = ZS[am];
            float2 Ah = ZH[ak], Bh = ZH[am];
            float2 w = cmul(cv, twI[i]);          // W_16384^k
            float Er = 0.5f*(As.x + Bs.x), Ei = 0.5f*(As.y - Bs.y);
            float Dr = 0.5f*(As.x - Bs.x), Di = 0.5f*(As.y + Bs.y);
            float sr = Er + w.x*Di + w.y*Dr;
            float si = Ei + w.y*Di - w.x*Dr;
            Er = 0.5f*(Ah.x + Bh.x); Ei = 0.5f*(Ah.y - Bh.y);
            Dr = 0.5f*(Ah.x - Bh.x); Di = 0.5f*(Ah.y + Bh.y);
            float hr = Er + w.x*Di + w.y*Dr;
            float hi = Ei + w.y*Di - w.x*Dr;
            hh[i] = hr*hr + hi*hi;
            hs[i] = hr*sr + hi*si;
        }
        __syncthreads();                          // all spectrum reads done; LDS free

        // -------- cum_h: wave shuffle scan over 16 waves --------
        const int SCANW = 16500;                  // 16 floats (upper half dead)
        const int EDG   = 16520;                  // 17 ints
        const int BINS  = 16544;                  // 16 floats
        const int TOT   = 16561;

        float run = 0.f;
        #pragma unroll
        for (int i = 0; i < 8; i++) run += ALPHA * hh[i];

        const int lane = t & 63, wid = t >> 6;
        float v = run;
        #pragma unroll
        for (int off = 1; off < 64; off <<= 1) {
            float o = __shfl_up(v, off, 64);
            if (lane >= off) v += o;
        }
        if (lane == 63) F[SCANW + wid] = v;
        __syncthreads();
        float wbase = 0.f;
        #pragma unroll
        for (int w2 = 0; w2 < 15; w2++) if (w2 < wid) wbase += F[SCANW + w2];
        float base2 = wbase + v - run;            // exclusive prefix

        float cum = base2;
        #pragma unroll
        for (int i = 0; i < 8; i++) {             // cum at phys(k)=k+(k>>5)
            cum += ALPHA * hh[i];
            int k = (t << 3) + i;
            F[k + (k >> 5)] = cum;
        }
        if (t == 1023) F[8448] = cum + ALPHA * h_nyq * h_nyq;   // cum_h[8192]
        __syncthreads();

        // -------- edges (searchsorted right) + bin init --------
        float total_h = F[8448];
        if (t < 17) {
            float target = (float)t * 0.0625f * total_h;
            int lo = 0, hi = 8193;
            while (lo < hi) {
                int mid = (lo + hi) >> 1;
                float vv = F[mid + (mid >> 5)];
                if (vv <= target) lo = mid + 1; else hi = mid;
            }
            I[EDG + t] = lo < 8192 ? lo : 8192;
        }
        if (t >= 64 && t < 80) F[BINS + (t - 64)] = 0.f;
        if (t == 80) F[TOT] = 0.f;
        __syncthreads();

        int e[17];
        #pragma unroll
        for (int i = 0; i < 17; i++) e[i] = I[EDG + i];

        float invs = 1.0f / sqrtf(total_h);
        float qs   = ALPHA * invs;

        // -------- segmented bin sums + total --------
        float tot = 0.f, acc = 0.f;
        int   cur = -1;
        #pragma unroll
        for (int i = 0; i < 8; i++) {
            int   k = (t << 3) + i;
            float r = qs * hs[i];
            tot += r;
            int bn = -1;                          // k in bin bn iff e[bn] < k <= e[bn+1]
            #pragma unroll
            for (int j = 0; j < 17; j++) bn += (e[j] < k) ? 1 : 0;
            if (bn != cur) {
                if (cur >= 0) atomicAdd(&F[BINS + cur], acc);
                acc = 0.f;
                cur = bn;
            }
            acc += r;
        }
        if (cur >= 0) atomicAdd(&F[BINS + cur], acc);

        #pragma unroll
        for (int off = 32; off > 0; off >>= 1) tot += __shfl_down(tot, off);
        if ((t & 63) == 0) atomicAdd(&F[TOT], tot);

        if (t == 0) {                             // Nyquist term (k = 8192)
            float rn = qs * (h_nyq * s_nyq);
            atomicAdd(&F[TOT], rn);
            int bn = -1;
            #pragma unroll
            for (int j = 0; j < 17; j++) bn += (e[j] < 8192) ? 1 : 0;
            if (bn >= 0) atomicAdd(&F[BINS + bn], rn);
        }
        __syncthreads();

        if (t == 0) {
            float total = F[TOT];
            float mean  = total * 0.0625f;
            float chisq = 0.f;
            #pragma unroll
            for (int j = 0; j < 16; j++) {
                float d = F[BINS + j] - mean;
                chisq += d * d;
            }
            out[row] = chisq * (16.0f / 15.0f);
        }
        // loop-top __syncthreads() protects BINS/TOT reads vs next stage-1 stores
    }
}

extern "C" void kernel_launch(void* const* d_in, const int* in_sizes, int n_in,
                              void* d_out, int out_size, void* d_ws, size_t ws_size,
                              hipStream_t stream) {
    const float* tmpl = (const float*)d_in[0];
    const float* strn = (const float*)d_in[1];
    float* outp = (float*)d_out;
    float2* ws  = (float2*)d_ws;                 // ~12.3 KiB twiddle tables

    int rows = in_sizes[0] / 16384;              // 1024
    int nblk = (rows + RPB - 1) / RPB;           // 256 persistent blocks (1 per CU)

    hipLaunchKernelGGL(init_tw, dim3(2), dim3(1024), 0, stream, ws);
    hipLaunchKernelGGL(chisq_kernel, dim3(nblk), dim3(1024), 0, stream,
                       tmpl, strn, ws, outp, rows);
}